// Round 4
// baseline (43.540 us; speedup 1.0000x reference)
//
#include <hip/hip_runtime.h>

typedef __attribute__((ext_vector_type(8))) short short8;
typedef __attribute__((ext_vector_type(4))) float f32x4;
typedef __attribute__((ext_vector_type(4))) unsigned u32x4;

__device__ __forceinline__ unsigned f2bf(float f) {
    unsigned u = __float_as_uint(f);
    return (u + 0x7fffu + ((u >> 16) & 1u)) >> 16;  // RNE float->bf16 bits
}
__device__ __forceinline__ unsigned pack2(float lo, float hi) {
    return f2bf(lo) | (f2bf(hi) << 16);
}

// x: (64,2,64,64,64) f32 ; W: (32,32,64,128) f32 ; out: (64,2,32,32,128) f32
// No LDS, no barriers. Block = 4 waves; wave wv owns f-range [32wv, 32wv+32),
// loops over 4 b-tiles of 16. W fragments loaded directly (strided dwords),
// packed to bf16 in-reg; x loaded dwordx4 per-wave (intra-block redundancy
// absorbed by L1/L2). Results stored per b-tile -> tiny accumulator state.
__global__ __launch_bounds__(256, 3) void cplx_dot_kernel(
    const float* __restrict__ x, const float* __restrict__ Wr,
    const float* __restrict__ Wi, const float* __restrict__ br,
    const float* __restrict__ bi, float* __restrict__ out)
{
    const int bid = blockIdx.x;          // 0..1023
    const int h = bid >> 5, w = bid & 31;
    const int t = threadIdx.x;
    const int wv = t >> 6, l = t & 63;
    const int lr = l & 15, lh = l >> 4;
    const int f0 = 32 * wv;

    // ---- W fragments: global strided dwords -> bf16 regs (64 loads/lane-wave) ----
    short8 wfr[2][2], wfi[2][2];         // [ft][kk]
    {
        const size_t wbase = ((size_t)(h * 32 + w) * 64) * 128;
        #pragma unroll
        for (int ft = 0; ft < 2; ++ft) {
            const int f = f0 + 16 * ft + lr;
            #pragma unroll
            for (int kk = 0; kk < 2; ++kk) {
                const int c0 = 32 * kk + 8 * lh;
                u32x4 pr, pi;
                #pragma unroll
                for (int j = 0; j < 4; ++j) {
                    float r0 = Wr[wbase + (size_t)(c0 + 2 * j) * 128 + f];
                    float r1 = Wr[wbase + (size_t)(c0 + 2 * j + 1) * 128 + f];
                    float i0 = Wi[wbase + (size_t)(c0 + 2 * j) * 128 + f];
                    float i1 = Wi[wbase + (size_t)(c0 + 2 * j + 1) * 128 + f];
                    pr[j] = pack2(r0, r1);
                    pi[j] = pack2(i0, i1);
                }
                wfr[ft][kk] = __builtin_bit_cast(short8, pr);
                wfi[ft][kk] = __builtin_bit_cast(short8, pi);
            }
        }
    }

    const float vbr0 = br[f0 + lr], vbr1 = br[f0 + 16 + lr];
    const float vbi0 = bi[f0 + lr], vbi1 = bi[f0 + 16 + lr];

    const size_t gimg = (size_t)64 * 64 * 64;   // re->im offset in x (floats)
    const size_t oimg = (size_t)32 * 32 * 128;  // re->im offset in out (floats)

    // x loads for one b-tile: brow = 16*mt + lr
#define LOAD_X(VR, VI, MT)                                                          \
    {                                                                               \
        const size_t gx = ((((size_t)(16 * (MT) + lr) * 2) * 64 + (16 + h)) * 64    \
                           + (16 + w)) * 64;                                        \
        _Pragma("unroll")                                                           \
        for (int kk = 0; kk < 2; ++kk) {                                            \
            const int c0 = 32 * kk + 8 * lh;                                        \
            VR[kk][0] = *(const f32x4*)(x + gx + c0);                               \
            VR[kk][1] = *(const f32x4*)(x + gx + c0 + 4);                           \
            VI[kk][0] = *(const f32x4*)(x + gx + gimg + c0);                        \
            VI[kk][1] = *(const f32x4*)(x + gx + gimg + c0 + 4);                    \
        }                                                                           \
    }

    // pack + 16 MFMA + bias/relu/store for one b-tile
#define STEP(VR, VI, MT)                                                            \
    {                                                                               \
        f32x4 accR[2], accI[2];                                                     \
        _Pragma("unroll")                                                           \
        for (int ft = 0; ft < 2; ++ft)                                              \
            _Pragma("unroll")                                                       \
            for (int j = 0; j < 4; ++j) { accR[ft][j] = 0.f; accI[ft][j] = 0.f; }   \
        _Pragma("unroll")                                                           \
        for (int kk = 0; kk < 2; ++kk) {                                            \
            u32x4 par, pai;                                                         \
            _Pragma("unroll")                                                       \
            for (int p = 0; p < 2; ++p) {                                           \
                par[2 * p]     = pack2(VR[kk][p][0], VR[kk][p][1]);                 \
                par[2 * p + 1] = pack2(VR[kk][p][2], VR[kk][p][3]);                 \
                pai[2 * p]     = pack2(VI[kk][p][0], VI[kk][p][1]);                 \
                pai[2 * p + 1] = pack2(VI[kk][p][2], VI[kk][p][3]);                 \
            }                                                                       \
            short8 arf = __builtin_bit_cast(short8, par);                           \
            short8 aif = __builtin_bit_cast(short8, pai);                           \
            short8 anf;                                                             \
            _Pragma("unroll")                                                       \
            for (int j = 0; j < 8; ++j) anf[j] = aif[j] ^ (short)0x8000;            \
            _Pragma("unroll")                                                       \
            for (int ft = 0; ft < 2; ++ft) {                                        \
                accR[ft] = __builtin_amdgcn_mfma_f32_16x16x32_bf16(arf, wfr[ft][kk], accR[ft], 0, 0, 0); \
                accR[ft] = __builtin_amdgcn_mfma_f32_16x16x32_bf16(anf, wfi[ft][kk], accR[ft], 0, 0, 0); \
                accI[ft] = __builtin_amdgcn_mfma_f32_16x16x32_bf16(arf, wfi[ft][kk], accI[ft], 0, 0, 0); \
                accI[ft] = __builtin_amdgcn_mfma_f32_16x16x32_bf16(aif, wfr[ft][kk], accI[ft], 0, 0, 0); \
            }                                                                       \
        }                                                                           \
        _Pragma("unroll")                                                           \
        for (int ft = 0; ft < 2; ++ft) {                                            \
            const int fc = f0 + 16 * ft + lr;                                       \
            const float bR = ft ? vbr1 : vbr0, bI = ft ? vbi1 : vbi0;               \
            _Pragma("unroll")                                                       \
            for (int j = 0; j < 4; ++j) {                                           \
                const int b = 16 * (MT) + 4 * lh + j;                               \
                size_t o = ((((size_t)b * 2) * 32 + h) * 32 + w) * 128 + fc;        \
                out[o] = fmaxf(accR[ft][j] + bR, 0.f);                              \
                out[o + oimg] = fmaxf(accI[ft][j] + bI, 0.f);                       \
            }                                                                       \
        }                                                                           \
    }

    // ---- 2-deep pipelined b-tile loop (static buffers A/B) ----
    f32x4 xrA[2][2], xiA[2][2], xrB[2][2], xiB[2][2];
    LOAD_X(xrA, xiA, 0)
    LOAD_X(xrB, xiB, 1)
    STEP(xrA, xiA, 0)
    LOAD_X(xrA, xiA, 2)
    STEP(xrB, xiB, 1)
    LOAD_X(xrB, xiB, 3)
    STEP(xrA, xiA, 2)
    STEP(xrB, xiB, 3)

#undef LOAD_X
#undef STEP
}

extern "C" void kernel_launch(void* const* d_in, const int* in_sizes, int n_in,
                              void* d_out, int out_size, void* d_ws, size_t ws_size,
                              hipStream_t stream) {
    const float* x  = (const float*)d_in[0];
    const float* Wr = (const float*)d_in[1];
    const float* Wi = (const float*)d_in[2];
    const float* br = (const float*)d_in[3];
    const float* bi = (const float*)d_in[4];
    float* out = (float*)d_out;
    hipLaunchKernelGGL(cplx_dot_kernel, dim3(1024), dim3(256), 0, stream,
                       x, Wr, Wi, br, bi, out);
}

// Round 5
// 33.183 us; speedup vs baseline: 1.3121x; 1.3121x over previous
//
#include <hip/hip_runtime.h>

typedef __attribute__((ext_vector_type(8))) short short8;
typedef __attribute__((ext_vector_type(4))) float f32x4;
typedef __attribute__((ext_vector_type(16))) float f32x16;
typedef __attribute__((ext_vector_type(4))) unsigned u32x4;

#define XSTR 72  // padded LDS row stride in bf16 elements (144 B)

__device__ __forceinline__ unsigned f2bf(float f) {
    unsigned u = __float_as_uint(f);
    return (u + 0x7fffu + ((u >> 16) & 1u)) >> 16;  // RNE float->bf16 bits
}
__device__ __forceinline__ unsigned pack2(float lo, float hi) {
    return f2bf(lo) | (f2bf(hi) << 16);
}

// x: (64,2,64,64,64) f32 ; W: (32,32,64,128) f32 ; out: (64,2,32,32,128) f32
// Block = one (h,w) position, 4 waves. Wave wv -> (b-half mt=wv>>1, f-half
// fhalf=wv&1). 32x32x16 MFMA: lane m=l&31 is the b-row (A) / f-col (B,C),
// kb=l>>5 selects the 8-wide k sub-block. W staged to LDS transposed [f][c];
// x loaded direct global->reg. Stores folded per f-tile, non-temporal.
__global__ __launch_bounds__(256, 3) void cplx_dot_kernel(
    const float* __restrict__ x, const float* __restrict__ Wr,
    const float* __restrict__ Wi, const float* __restrict__ br,
    const float* __restrict__ bi, float* __restrict__ out)
{
    __shared__ __align__(16) short sWr[128 * XSTR];
    __shared__ __align__(16) short sWi[128 * XSTR];

    const int bid = blockIdx.x;          // 0..1023
    const int h = bid >> 5, w = bid & 31;
    const int t = threadIdx.x;
    const int wv = t >> 6, l = t & 63;
    const int m = l & 31, kb = l >> 5;   // b-row / f-col ; k sub-block
    const int mt = wv >> 1, fhalf = wv & 1;

    const size_t gimg = (size_t)64 * 64 * 64;   // re->im offset in x (floats)
    const size_t oimg = (size_t)32 * 32 * 128;  // re->im offset in out (floats)

    // ---- issue x loads (raw f32, stay in flight during W load+stage) ----
    // lane needs x[32*mt+m][c], c = 16*kk + 8*kb .. +8, kk=0..3
    const int brow = 32 * mt + m;
    const size_t gx = ((((size_t)brow * 2) * 64 + (16 + h)) * 64 + (16 + w)) * 64;
    f32x4 vr[4][2], vi[4][2];
    #pragma unroll
    for (int kk = 0; kk < 4; ++kk) {
        const int c0 = 16 * kk + 8 * kb;
        vr[kk][0] = *(const f32x4*)(x + gx + c0);
        vr[kk][1] = *(const f32x4*)(x + gx + c0 + 4);
        vi[kk][0] = *(const f32x4*)(x + gx + gimg + c0);
        vi[kk][1] = *(const f32x4*)(x + gx + gimg + c0 + 4);
    }

    // ---- W slice -> LDS bf16 transposed [f][c] (same staging as R2) ----
    {
        const int g = t & 31, cg = t >> 5;   // g: float4 group along f ; cg: c-octet
        const size_t wbase = (((size_t)h * 32 + w) * 64) * 128;
        f32x4 rr[8], ri[8];
        #pragma unroll
        for (int i = 0; i < 8; ++i) {
            size_t off = wbase + (size_t)(8 * cg + i) * 128 + 4 * g;
            rr[i] = *(const f32x4*)(Wr + off);
            ri[i] = *(const f32x4*)(Wi + off);
        }
        #pragma unroll
        for (int j = 0; j < 4; ++j) {        // column f = 4g+j, c = 8cg..8cg+7
            u32x4 pr, pi;
            pr[0] = pack2(rr[0][j], rr[1][j]); pr[1] = pack2(rr[2][j], rr[3][j]);
            pr[2] = pack2(rr[4][j], rr[5][j]); pr[3] = pack2(rr[6][j], rr[7][j]);
            pi[0] = pack2(ri[0][j], ri[1][j]); pi[1] = pack2(ri[2][j], ri[3][j]);
            pi[2] = pack2(ri[4][j], ri[5][j]); pi[3] = pack2(ri[6][j], ri[7][j]);
            *(u32x4*)&sWr[(4 * g + j) * XSTR + 8 * cg] = pr;
            *(u32x4*)&sWi[(4 * g + j) * XSTR + 8 * cg] = pi;
        }
    }

    // ---- pack x -> bf16 A-fragments (x has arrived; W stage waited on it) ----
    short8 ar[4], ai[4], an[4];
    #pragma unroll
    for (int kk = 0; kk < 4; ++kk) {
        u32x4 pr, pi;
        #pragma unroll
        for (int p = 0; p < 2; ++p) {
            pr[2 * p]     = pack2(vr[kk][p][0], vr[kk][p][1]);
            pr[2 * p + 1] = pack2(vr[kk][p][2], vr[kk][p][3]);
            pi[2 * p]     = pack2(vi[kk][p][0], vi[kk][p][1]);
            pi[2 * p + 1] = pack2(vi[kk][p][2], vi[kk][p][3]);
        }
        ar[kk] = __builtin_bit_cast(short8, pr);
        ai[kk] = __builtin_bit_cast(short8, pi);
        #pragma unroll
        for (int j = 0; j < 8; ++j) an[kk][j] = ai[kk][j] ^ (short)0x8000;  // -xi
    }
    __syncthreads();

    // ---- per f-tile: 16 MFMAs + bias/relu + nt stores ----
    #pragma unroll
    for (int ft = 0; ft < 2; ++ft) {
        const int f = 64 * fhalf + 32 * ft + m;
        f32x16 accR = {}, accI = {};
        #pragma unroll
        for (int kk = 0; kk < 4; ++kk) {
            const int c0 = 16 * kk + 8 * kb;
            short8 wr_ = *(const short8*)&sWr[f * XSTR + c0];
            short8 wi_ = *(const short8*)&sWi[f * XSTR + c0];
            accR = __builtin_amdgcn_mfma_f32_32x32x16_bf16(ar[kk], wr_, accR, 0, 0, 0);
            accR = __builtin_amdgcn_mfma_f32_32x32x16_bf16(an[kk], wi_, accR, 0, 0, 0);
            accI = __builtin_amdgcn_mfma_f32_32x32x16_bf16(ar[kk], wi_, accI, 0, 0, 0);
            accI = __builtin_amdgcn_mfma_f32_32x32x16_bf16(ai[kk], wr_, accI, 0, 0, 0);
        }
        const float bR = br[f], bI = bi[f];
        // C/D layout (m74/m101): col = lane&31, row = (reg&3)+8*(reg>>2)+4*(lane>>5)
        #pragma unroll
        for (int r = 0; r < 16; ++r) {
            const int row = (r & 3) + 8 * (r >> 2) + 4 * kb;
            const int b = 32 * mt + row;
            size_t o = ((((size_t)b * 2) * 32 + h) * 32 + w) * 128 + f;
            __builtin_nontemporal_store(fmaxf(accR[r] + bR, 0.f), out + o);
            __builtin_nontemporal_store(fmaxf(accI[r] + bI, 0.f), out + o + oimg);
        }
    }
}

extern "C" void kernel_launch(void* const* d_in, const int* in_sizes, int n_in,
                              void* d_out, int out_size, void* d_ws, size_t ws_size,
                              hipStream_t stream) {
    const float* x  = (const float*)d_in[0];
    const float* Wr = (const float*)d_in[1];
    const float* Wi = (const float*)d_in[2];
    const float* br = (const float*)d_in[3];
    const float* bi = (const float*)d_in[4];
    float* out = (float*)d_out;
    hipLaunchKernelGGL(cplx_dot_kernel, dim3(1024), dim3(256), 0, stream,
                       x, Wr, Wi, br, bi, out);
}

// Round 6
// 30.689 us; speedup vs baseline: 1.4187x; 1.0813x over previous
//
#include <hip/hip_runtime.h>

typedef __attribute__((ext_vector_type(8))) short short8;
typedef __attribute__((ext_vector_type(4))) float f32x4;
typedef __attribute__((ext_vector_type(2))) unsigned u32x2;
typedef __attribute__((ext_vector_type(4))) unsigned u32x4;

#define XSTR 72  // padded LDS row stride in bf16 elements (144 B)

__device__ __forceinline__ unsigned f2bf(float f) {
    unsigned u = __float_as_uint(f);
    return (u + 0x7fffu + ((u >> 16) & 1u)) >> 16;  // RNE float->bf16 bits
}
__device__ __forceinline__ unsigned pack2(float lo, float hi) {
    return f2bf(lo) | (f2bf(hi) << 16);
}

// x: (64,2,64,64,64) f32 ; W: (32,32,64,128) f32 ; out: (64,2,32,32,128) f32
// R2 structure + counted-vmcnt phase split: W staged in two c-halves with raw
// s_barrier (lgkmcnt(0) only, NO vmcnt drain) so kk=0 compute overlaps the
// half-1 global loads still in flight. Stores folded per f-tile in kk=1.
__global__ __launch_bounds__(256, 3) void cplx_dot_kernel(
    const float* __restrict__ x, const float* __restrict__ Wr,
    const float* __restrict__ Wi, const float* __restrict__ br,
    const float* __restrict__ bi, float* __restrict__ out)
{
    __shared__ __align__(16) short sWr[128 * XSTR];
    __shared__ __align__(16) short sWi[128 * XSTR];

    const int bid = blockIdx.x;          // 0..1023
    const int h = bid >> 5, w = bid & 31;
    const int t = threadIdx.x;
    const int wv = t >> 6, l = t & 63;
    const int lr = l & 15, lh = l >> 4;
    const int g = t & 31, cg = t >> 5;   // f-quad 4g ; c-quad 4cg

    const size_t gimg = (size_t)64 * 64 * 64;   // re->im offset in x (floats)
    const size_t oimg = (size_t)32 * 32 * 128;  // re->im offset in out (floats)

    // ---- issue x loads FIRST (arrive earliest; pack_x waits only on these) ----
    const int brow = 16 * wv + lr;
    const size_t gx = ((((size_t)brow * 2) * 64 + (16 + h)) * 64 + (16 + w)) * 64;
    f32x4 vr[2][2], vi[2][2];
    #pragma unroll
    for (int kk = 0; kk < 2; ++kk) {
        const int c0 = 32 * kk + 8 * lh;
        vr[kk][0] = *(const f32x4*)(x + gx + c0);
        vr[kk][1] = *(const f32x4*)(x + gx + c0 + 4);
        vi[kk][0] = *(const f32x4*)(x + gx + gimg + c0);
        vi[kk][1] = *(const f32x4*)(x + gx + gimg + c0 + 4);
    }

    // ---- issue W loads: half0 (c 0..31) then half1 (c 32..63) ----
    // thread owns 4c x 4f patch per half: rows c = 4cg+i (+32), cols f = 4g..4g+3
    const size_t wbase = (((size_t)h * 32 + w) * 64) * 128;
    f32x4 rr0[4], ri0[4], rr1[4], ri1[4];
    #pragma unroll
    for (int i = 0; i < 4; ++i) {
        size_t off = wbase + (size_t)(4 * cg + i) * 128 + 4 * g;
        rr0[i] = *(const f32x4*)(Wr + off);
        ri0[i] = *(const f32x4*)(Wi + off);
    }
    #pragma unroll
    for (int i = 0; i < 4; ++i) {
        size_t off = wbase + (size_t)(32 + 4 * cg + i) * 128 + 4 * g;
        rr1[i] = *(const f32x4*)(Wr + off);
        ri1[i] = *(const f32x4*)(Wi + off);
    }

    // ---- pack x -> A fragments (waits x only; W still in flight) ----
    short8 ar[2], ai[2];
    #pragma unroll
    for (int kk = 0; kk < 2; ++kk) {
        u32x4 pr, pi;
        #pragma unroll
        for (int p = 0; p < 2; ++p) {
            pr[2 * p]     = pack2(vr[kk][p][0], vr[kk][p][1]);
            pr[2 * p + 1] = pack2(vr[kk][p][2], vr[kk][p][3]);
            pi[2 * p]     = pack2(vi[kk][p][0], vi[kk][p][1]);
            pi[2 * p + 1] = pack2(vi[kk][p][2], vi[kk][p][3]);
        }
        ar[kk] = __builtin_bit_cast(short8, pr);
        ai[kk] = __builtin_bit_cast(short8, pi);
    }

    // ---- stage half0 (partial vmcnt wait: half1 loads stay outstanding) ----
    #pragma unroll
    for (int j = 0; j < 4; ++j) {        // f-row 4g+j, cols 4cg..4cg+3
        u32x2 pr, pi;
        pr[0] = pack2(rr0[0][j], rr0[1][j]); pr[1] = pack2(rr0[2][j], rr0[3][j]);
        pi[0] = pack2(ri0[0][j], ri0[1][j]); pi[1] = pack2(ri0[2][j], ri0[3][j]);
        *(u32x2*)&sWr[(4 * g + j) * XSTR + 4 * cg] = pr;
        *(u32x2*)&sWi[(4 * g + j) * XSTR + 4 * cg] = pi;
    }

    // raw barrier: drain LDS writes only, leave global loads in flight
    asm volatile("s_waitcnt lgkmcnt(0)\n\ts_barrier" ::: "memory");

    // ---- kk=0 compute (c 0..31) — hidden under half1's HBM stream ----
    f32x4 accR[8], accI[8];
    #pragma unroll
    for (int ft = 0; ft < 8; ++ft)
        #pragma unroll
        for (int j = 0; j < 4; ++j) { accR[ft][j] = 0.f; accI[ft][j] = 0.f; }

    {
        short8 an0;
        #pragma unroll
        for (int j = 0; j < 8; ++j) an0[j] = ai[0][j] ^ (short)0x8000;  // -xi
        const int c0 = 8 * lh;
        #pragma unroll
        for (int ft = 0; ft < 8; ++ft) {
            short8 wr_ = *(const short8*)&sWr[(16 * ft + lr) * XSTR + c0];
            short8 wi_ = *(const short8*)&sWi[(16 * ft + lr) * XSTR + c0];
            accR[ft] = __builtin_amdgcn_mfma_f32_16x16x32_bf16(ar[0], wr_, accR[ft], 0, 0, 0);
            accR[ft] = __builtin_amdgcn_mfma_f32_16x16x32_bf16(an0,   wi_, accR[ft], 0, 0, 0);
            accI[ft] = __builtin_amdgcn_mfma_f32_16x16x32_bf16(ar[0], wi_, accI[ft], 0, 0, 0);
            accI[ft] = __builtin_amdgcn_mfma_f32_16x16x32_bf16(ai[0], wr_, accI[ft], 0, 0, 0);
        }
    }

    // ---- stage half1 (vmcnt waits for half1 arrival here) ----
    #pragma unroll
    for (int j = 0; j < 4; ++j) {
        u32x2 pr, pi;
        pr[0] = pack2(rr1[0][j], rr1[1][j]); pr[1] = pack2(rr1[2][j], rr1[3][j]);
        pi[0] = pack2(ri1[0][j], ri1[1][j]); pi[1] = pack2(ri1[2][j], ri1[3][j]);
        *(u32x2*)&sWr[(4 * g + j) * XSTR + 32 + 4 * cg] = pr;
        *(u32x2*)&sWi[(4 * g + j) * XSTR + 32 + 4 * cg] = pi;
    }

    asm volatile("s_waitcnt lgkmcnt(0)\n\ts_barrier" ::: "memory");

    // ---- bias (tiny, L2-hot) ----
    float vbr[8], vbi[8];
    #pragma unroll
    for (int ft = 0; ft < 8; ++ft) { vbr[ft] = br[16 * ft + lr]; vbi[ft] = bi[16 * ft + lr]; }

    // ---- kk=1 compute (c 32..63) + folded bias/relu/stores per f-tile ----
    {
        short8 an1;
        #pragma unroll
        for (int j = 0; j < 8; ++j) an1[j] = ai[1][j] ^ (short)0x8000;
        const int c0 = 32 + 8 * lh;
        #pragma unroll
        for (int ft = 0; ft < 8; ++ft) {
            short8 wr_ = *(const short8*)&sWr[(16 * ft + lr) * XSTR + c0];
            short8 wi_ = *(const short8*)&sWi[(16 * ft + lr) * XSTR + c0];
            accR[ft] = __builtin_amdgcn_mfma_f32_16x16x32_bf16(ar[1], wr_, accR[ft], 0, 0, 0);
            accR[ft] = __builtin_amdgcn_mfma_f32_16x16x32_bf16(an1,   wi_, accR[ft], 0, 0, 0);
            accI[ft] = __builtin_amdgcn_mfma_f32_16x16x32_bf16(ar[1], wi_, accI[ft], 0, 0, 0);
            accI[ft] = __builtin_amdgcn_mfma_f32_16x16x32_bf16(ai[1], wr_, accI[ft], 0, 0, 0);

            const int fc = 16 * ft + lr;
            #pragma unroll
            for (int j = 0; j < 4; ++j) {
                const int b = 16 * wv + 4 * lh + j;
                size_t o = ((((size_t)b * 2) * 32 + h) * 32 + w) * 128 + fc;
                out[o]        = fmaxf(accR[ft][j] + vbr[ft], 0.f);
                out[o + oimg] = fmaxf(accI[ft][j] + vbi[ft], 0.f);
            }
        }
    }
}

extern "C" void kernel_launch(void* const* d_in, const int* in_sizes, int n_in,
                              void* d_out, int out_size, void* d_ws, size_t ws_size,
                              hipStream_t stream) {
    const float* x  = (const float*)d_in[0];
    const float* Wr = (const float*)d_in[1];
    const float* Wi = (const float*)d_in[2];
    const float* br = (const float*)d_in[3];
    const float* bi = (const float*)d_in[4];
    float* out = (float*)d_out;
    hipLaunchKernelGGL(cplx_dot_kernel, dim3(1024), dim3(256), 0, stream,
                       x, Wr, Wi, br, bi, out);
}